// Round 1
// baseline (165.517 us; speedup 1.0000x reference)
//
#include <hip/hip_runtime.h>

// Problem constants (fixed by setup_inputs):
//   n=4, b=8192, a=32, c_in=32, d_out=32, n_basis=36 (4 radii x 9 SH), ck=1152
// inputs: [0] input (4,32,8192) f32, [1] coords (4,8192,3) f32,
//         [2] relative_mask (4,8192,32) f32, [3] W (32,32,36) f32,
//         [4] neighbors (4,8192,32) i32
// output: (4,32,8192) f32

#define PPB 8  // points per block (8 consecutive b within one n; 8192%8==0)

// ---------------- prep: transpose input to (n,b,c); permute W to Wq[ck][dq] ----------------
// Wq[ck*32 + (d&7)*4 + (d>>3)] = W[d*1152 + ck]  -> float4 at (ck*32 + d4*4) covers d = d4+8m
__global__ __launch_bounds__(256) void prep_kernel(
    const float* __restrict__ inp, const float* __restrict__ W,
    float* __restrict__ inp_t, float* __restrict__ Wq)
{
    int tid = blockIdx.x * 256 + threadIdx.x;
    if (tid < 4 * 32 * 8192) {
        int c = tid & 31;
        int b = (tid >> 5) & 8191;
        int n = tid >> 18;
        inp_t[tid] = inp[((n << 5) + c) * 8192 + b];
    } else {
        int t2 = tid - 4 * 32 * 8192;
        if (t2 < 1152 * 32) {
            int d  = t2 & 31;
            int ck = t2 >> 5;
            Wq[(ck << 5) + ((d & 7) << 2) + (d >> 3)] = W[d * 1152 + ck];
        }
    }
}

// ---------------- main fused kernel ----------------
__global__ __launch_bounds__(256) void se3_main(
    const float* __restrict__ inp_t, const float* __restrict__ coords,
    const float* __restrict__ rmask, const int* __restrict__ neigh,
    const float* __restrict__ Wq, float* __restrict__ out)
{
    // geom row (20 floats, 80B = 16B-aligned, 20%32 spreads banks):
    //   [0..3]=rb0..3 (mask folded), [4..12]=Y0..8, rest pad
    __shared__ float geom[4][32][20];                 // 10,240 B
    __shared__ int   idxs[4][32];                     //    512 B
    __shared__ __align__(16) float Mbuf[1152 * 9];    // 41,472 B  M[ck][p] (row pad 9)
    // after phase 2, Mbuf is reused as ored[32][8][33] (8448 floats)

    const int tid  = threadIdx.x;
    const int lane = tid & 63;
    const int w    = tid >> 6;     // wave id 0..3
    const int c    = lane & 31;    // c index / neighbor-geometry lane
    const int kh   = lane >> 5;    // k-half: shells {2kh, 2kh+1}

    const int gp0      = blockIdx.x << 3;   // first global point = n*8192+b0
    const int n_       = gp0 >> 13;
    const int b0       = gp0 & 8191;
    const int nbase_pt = n_ << 13;          // n*8192

    // ================= Phase 1: each wave builds M for 2 points =================
    for (int pw = 0; pw < 2; ++pw) {
        const int p  = (w << 1) | pw;       // 0..7 within block
        const int gp = gp0 + p;

        // geometry for neighbor a = c (both wave halves compute redundantly)
        const int   abase = (gp << 5) | c;
        const int   idx   = neigh[abase];
        const float msk   = rmask[abase];
        const float cx = coords[gp * 3 + 0];
        const float cy = coords[gp * 3 + 1];
        const float cz = coords[gp * 3 + 2];
        const int   nb = nbase_pt + idx;
        const float dx = coords[nb * 3 + 0] - cx;
        const float dy = coords[nb * 3 + 1] - cy;
        const float dz = coords[nb * 3 + 2] - cz;
        const float r   = sqrtf(dx * dx + dy * dy + dz * dz);
        const float inv = 1.0f / (r + 1e-8f);
        const float x = dx * inv, y = dy * inv, z = dz * inv;
        const float Y0 = 0.28209479f;
        const float Y1 = 0.48860251f * x;
        const float Y2 = 0.48860251f * y;
        const float Y3 = 0.48860251f * z;
        const float Y4 = 1.09254843f * x * y;
        const float Y5 = 1.09254843f * y * z;
        const float Y6 = 0.31539157f * (3.0f * z * z - 1.0f);
        const float Y7 = 1.09254843f * x * z;
        const float Y8 = 0.54627421f * (x * x - y * y);
        const float t0 = (r - 0.5f) * 2.0f;
        const float t1 = (r - 1.0f) * 2.0f;
        const float t2 = (r - 1.5f) * 2.0f;
        const float t3 = (r - 2.0f) * 2.0f;
        const float rb0 = __expf(-t0 * t0) * msk;
        const float rb1 = __expf(-t1 * t1) * msk;
        const float rb2 = __expf(-t2 * t2) * msk;
        const float rb3 = __expf(-t3 * t3) * msk;

        if (lane < 32) {
            float* g = &geom[w][c][0];
            *(float4*)(g + 0) = make_float4(rb0, rb1, rb2, rb3);
            *(float4*)(g + 4) = make_float4(Y0, Y1, Y2, Y3);
            *(float4*)(g + 8) = make_float4(Y4, Y5, Y6, Y7);
            g[12] = Y8;
            idxs[w][c] = idx;
        }
        // same-wave LDS write->read: DS pipe is in-order per wave; no barrier needed.

        float acc[18];
        #pragma unroll
        for (int j = 0; j < 18; ++j) acc[j] = 0.0f;

        const int featbase = nbase_pt << 5;   // (n*8192)*32
        #pragma unroll 4
        for (int a = 0; a < 32; ++a) {
            const int    ia  = idxs[w][a];
            const float  f   = inp_t[featbase + (ia << 5) + c];   // coalesced 128B
            const float* g   = &geom[w][a][0];
            const float2 rbp = *(const float2*)(g + (kh << 1));   // rb[2kh], rb[2kh+1]
            const float4 y03 = *(const float4*)(g + 4);
            const float4 y47 = *(const float4*)(g + 8);
            const float  y8  = g[12];
            const float fA = f * rbp.x, fB = f * rbp.y;
            acc[0] += fA * y03.x;  acc[9]  += fB * y03.x;
            acc[1] += fA * y03.y;  acc[10] += fB * y03.y;
            acc[2] += fA * y03.z;  acc[11] += fB * y03.z;
            acc[3] += fA * y03.w;  acc[12] += fB * y03.w;
            acc[4] += fA * y47.x;  acc[13] += fB * y47.x;
            acc[5] += fA * y47.y;  acc[14] += fB * y47.y;
            acc[6] += fA * y47.z;  acc[15] += fB * y47.z;
            acc[7] += fA * y47.w;  acc[16] += fB * y47.w;
            acc[8] += fA * y8;     acc[17] += fB * y8;
        }

        // M[ck][p], ck = c*36 + kh*18 + j   (row pad 9 -> 4-way max write conflicts)
        const int ckb = c * 36 + kh * 18;
        #pragma unroll
        for (int j = 0; j < 18; ++j)
            Mbuf[(ckb + j) * 9 + p] = acc[j];
    }
    __syncthreads();

    // ================= Phase 2: out(32d, 8p) = Wq(1152, 32d) . M(1152, 8p) =================
    const int d4 = tid & 7;    // d in {d4, d4+8, d4+16, d4+24}
    const int g  = tid >> 3;   // 32 ck-groups of 36
    float o[4][8];
    #pragma unroll
    for (int m = 0; m < 4; ++m)
        #pragma unroll
        for (int p = 0; p < 8; ++p) o[m][p] = 0.0f;

    #pragma unroll 2
    for (int t = 0; t < 36; ++t) {
        const int    ck = g * 36 + t;
        const float4 wv = *(const float4*)&Wq[(ck << 5) + (d4 << 2)];  // coalesced 128B/8 lanes
        const float* mr = &Mbuf[ck * 9];
        #pragma unroll
        for (int p = 0; p < 8; ++p) {
            const float mv = mr[p];       // broadcast within g-group
            o[0][p] += wv.x * mv;
            o[1][p] += wv.y * mv;
            o[2][p] += wv.z * mv;
            o[3][p] += wv.w * mv;
        }
    }
    __syncthreads();   // all M reads done -> safe to alias Mbuf as reduction buffer

    float* ored = Mbuf;   // ored[d][p][g] with g-dim padded to 33
    #pragma unroll
    for (int m = 0; m < 4; ++m) {
        const int d = d4 + (m << 3);
        #pragma unroll
        for (int p = 0; p < 8; ++p)
            ored[(d * 8 + p) * 33 + g] = o[m][p];
    }
    __syncthreads();

    {
        const int d = tid >> 3;
        const int p = tid & 7;
        const float* rr = &ored[(d * 8 + p) * 33];
        float s = 0.0f;
        #pragma unroll
        for (int gg = 0; gg < 32; ++gg) s += rr[gg];
        out[(((n_ << 5) + d) << 13) + b0 + p] = s;
    }
}

extern "C" void kernel_launch(void* const* d_in, const int* in_sizes, int n_in,
                              void* d_out, int out_size, void* d_ws, size_t ws_size,
                              hipStream_t stream)
{
    const float* inp    = (const float*)d_in[0];  // (4,32,8192)
    const float* coords = (const float*)d_in[1];  // (4,8192,3)
    const float* rmask  = (const float*)d_in[2];  // (4,8192,32)
    const float* W      = (const float*)d_in[3];  // (32,32,36)
    const int*   neigh  = (const int*)d_in[4];    // (4,8192,32)
    float*       outp   = (float*)d_out;

    float* inp_t = (float*)d_ws;                       // 4*8192*32 f32 = 4 MB
    float* Wq    = (float*)((char*)d_ws + 4u * 32u * 8192u * 4u);  // 1152*32 f32 = 147 KB

    // prep: 1,048,576 + 36,864 = 1,085,440 threads = 4240 blocks exactly
    prep_kernel<<<4240, 256, 0, stream>>>(inp, W, inp_t, Wq);

    // main: 32768 points / 8 per block
    se3_main<<<4096, 256, 0, stream>>>(inp_t, coords, rmask, neigh, Wq, outp);
}